// Round 17
// baseline (796.851 us; speedup 1.0000x reference)
//
#include <hip/hip_runtime.h>
#include <stdint.h>

#define SEQ      1024
#define NT       128
#define NBATCH   256
#define MID      512
#define WS_STRIDE 132       // 128 floats + kSum
#define NB4      4          // batches per chain block

// 16 NAMED u32 weight regs (bf16 pairs) = 16 VGPRs, batch-independent -> shared
// across the 4 batches. R13-proven resident (f32 weights spill: R14).
#define RALL(X) X(0) X(1) X(2) X(3) X(4) X(5) X(6) X(7) \
                X(8) X(9) X(10) X(11) X(12) X(13) X(14) X(15)
#define DECLW(k) uint32_t W##k;
#define INITW(k) { \
    float f0_ = __expf(wbase[(2 * (k)    ) * wstr]); \
    float f1_ = __expf(wbase[(2 * (k) + 1) * wstr]); \
    asm("v_cvt_pk_bf16_f32 %0, %1, %2" : "=v"(W##k) : "v"(f0_), "v"(f1_)); }
#define PINW(k)  asm volatile("" : "+v"(W##k));

// emulated bf16-pair dot (R13-proven): 6 ops/pair
#define DOT2ACC(a, su, wu) { \
    a = fmaf(__uint_as_float((wu) << 16),         __uint_as_float((su) << 16),         a); \
    a = fmaf(__uint_as_float((wu) & 0xffff0000u), __uint_as_float((su) & 0xffff0000u), a); }

#define MQ(c, k0, k1, k2, k3) { \
    uint4 u_ = *(const uint4*)(gp + 4 * (c)); \
    DOT2ACC(a0, u_.x, W##k0); \
    DOT2ACC(a1, u_.y, W##k1); \
    DOT2ACC(a2, u_.z, W##k2); \
    DOT2ACC(a3, u_.w, W##k3); }

// 32-tag quarter dot + cross-q combine (partners = adjacent lanes)
#define MATVEC32(S_) { \
    float a0 = 0.f, a1 = 0.f, a2 = 0.f, a3 = 0.f; \
    MQ(0,0,1,2,3) MQ(1,4,5,6,7) MQ(2,8,9,10,11) MQ(3,12,13,14,15) \
    S_ = (a0 + a1) + (a2 + a3); \
    S_ += __shfl_xor(S_, 1, 64); \
    S_ += __shfl_xor(S_, 2, 64); }

#define BF16_STORE(bufp_, val_) { \
    uint32_t pk_; \
    asm("v_cvt_pk_bf16_f32 %0, %1, %2" : "=v"(pk_) : "v"(val_), "v"(val_)); \
    ((unsigned short*)(bufp_))[jt] = (unsigned short)(pk_ & 0xffffu); }

// blocks [0,64):    forward chains, batches 4*blk .. 4*blk+3 (steps 1..512)
// blocks [64,128):  backward chains, batches 4*(blk-64) ..    (steps 1023..513)
// blocks [128,160): score gathers (8 batches each)
__global__ __launch_bounds__(512) void crf_chains(
    const float* __restrict__ emissions,   // [B, SEQ, NT]
    const float* __restrict__ transitions, // [NT, NT]
    const int*   __restrict__ tags,        // [B, SEQ]
    const float* __restrict__ mask,        // [B, SEQ]
    float* __restrict__ out,               // [1]
    float* __restrict__ ws)                // [2*256*132]
{
    const int blk = blockIdx.x;
    const int tid = threadIdx.x;

    if (blk >= 2 * (NBATCH / NB4)) {
        // ---------------- score blocks ----------------
        int b    = (blk - 2 * (NBATCH / NB4)) * 8 + (tid >> 6);
        int lane = tid & 63;
        const float* emb = emissions + (size_t)b * SEQ * NT;
        const int*   tgb = tags + (size_t)b * SEQ;
        const float* mkb = mask + (size_t)b * SEQ;
        float sc = 0.f;
        for (int t = lane; t < SEQ; t += 64) {
            int   tg = tgb[t];
            float mt = mkb[t];
            sc += emb[t * NT + tg] * mt;
            if (t >= 1) sc += transitions[tgb[t - 1] * NT + tg] * mt;
        }
#pragma unroll
        for (int o = 32; o > 0; o >>= 1) sc += __shfl_down(sc, o, 64);
        if (lane == 0) atomicAdd(out, -sc * (1.0f / NBATCH));
        return;
    }

    // ---------------- chain block: 4 batches ----------------
    // per-batch state = 64 u32 bf16 pairs, double-buffered (per-batch parity)
    __shared__ __align__(16) uint32_t buf[2][NB4][NT / 2];

    const int jt = tid >> 2;   // owned output tag 0..127
    const int q  = tid & 3;    // predecessor quarter (32 tags)

    const bool fwd = (blk < NBATCH / NB4);
    const int  b0  = (fwd ? blk : blk - NBATCH / NB4) * NB4;

    // fwd: expT[32q+2k][jt] (col jt, stride NT); bwd: expT[jt][32q+2k] (row)
    const float* wbase = fwd ? (transitions + (size_t)(32 * q) * NT + jt)
                             : (transitions + (size_t)jt * NT + 32 * q);
    const int    wstr  = fwd ? NT : 1;

    RALL(DECLW)
    RALL(INITW)
    RALL(PINW)

    const float* embi[NB4];
    const float* mkbi[NB4];
#pragma unroll
    for (int i = 0; i < NB4; ++i) {
        embi[i] = emissions + (size_t)(b0 + i) * SEQ * NT;
        mkbi[i] = mask + (size_t)(b0 + i) * SEQ;
    }

    int   kSum[NB4] = {0, 0, 0, 0};
    int   pb[NB4]   = {0, 0, 0, 0};
    float gcur[NB4], beta[NB4];
    float E0[NB4], E1[NB4], M0[NB4], M1[NB4];

#pragma unroll
    for (int i = 0; i < NB4; ++i) {
        beta[i] = 1.0f;
        if (fwd) {
            gcur[i] = __expf(embi[i][jt]);
            if (q == 0) BF16_STORE(buf[0][i], gcur[i]);
            E0[i] = embi[i][1 * NT + jt];  E1[i] = embi[i][2 * NT + jt];
            M0[i] = mkbi[i][1];            M1[i] = mkbi[i][2];
        } else {
            float w0 = __expf(embi[i][(size_t)(SEQ - 1) * NT + jt]);  // w_1023
            if (q == 0) BF16_STORE(buf[0][i], w0);
            E0[i] = embi[i][(size_t)(SEQ - 2) * NT + jt];
            E1[i] = embi[i][(size_t)(SEQ - 3) * NT + jt];
            M0[i] = mkbi[i][SEQ - 1];      M1[i] = mkbi[i][SEQ - 2];
        }
    }
    __syncthreads();

    if (fwd) {
        // ---------- forward: 512 steps, t = 1+s ----------
        for (int s = 0; s < MID; ++s) {
#pragma unroll
            for (int i = 0; i < NB4; ++i) {
                float En = embi[i][(size_t)(3 + s) * NT + jt];   // <= 514
                float Mn = mkbi[i][3 + s];
                if (M0[i] != 0.0f) {
                    const uint32_t* gp = buf[pb[i]][i] + 16 * q;
                    uint32_t anchor = buf[pb[i]][i][0];
                    float sres;
                    MATVEC32(sres);
                    int   e  = (int)((anchor >> 7) & 0xff);      // bf16 exp of tag0
                    float rc = __uint_as_float((uint32_t)(254 - e) << 23);
                    kSum[i] += e - 127;
                    if (q == 0) {
                        gcur[i] = sres * rc * __expf(E0[i]);
                        BF16_STORE(buf[pb[i] ^ 1][i], gcur[i]);
                    }
                    pb[i] ^= 1;
                }
                E0[i] = E1[i]; E1[i] = En; M0[i] = M1[i]; M1[i] = Mn;
            }
            __syncthreads();
        }
#pragma unroll
        for (int i = 0; i < NB4; ++i) {
            float* wsb = ws + (size_t)(b0 + i) * WS_STRIDE;
            if (q == 0)  wsb[jt] = gcur[i];       // alpha_512 (pow2-scaled)
            if (tid == 0) wsb[128] = (float)kSum[i];
        }
    } else {
        // ---------- backward: 511 steps, t = 1023-s; buf holds w = beta.*expE ----------
        for (int s = 0; s < MID - 1; ++s) {
#pragma unroll
            for (int i = 0; i < NB4; ++i) {
                float En = embi[i][(size_t)(SEQ - 4 - s) * NT + jt];  // >= 510
                float Mn = mkbi[i][SEQ - 3 - s];
                {
                    const uint32_t* gp = buf[pb[i]][i] + 16 * q;
                    uint32_t anchor = buf[pb[i]][i][0];
                    float sres;
                    MATVEC32(sres);
                    int   e  = (int)((anchor >> 7) & 0xff);
                    float rc = __uint_as_float((uint32_t)(254 - e) << 23);
                    kSum[i] += e - 127;
                    float bn = (M0[i] != 0.0f) ? sres * rc : beta[i] * rc;
                    beta[i] = bn;
                    if (q == 0) {
                        float g = bn * __expf(E0[i]);   // w_{t-1}
                        BF16_STORE(buf[pb[i] ^ 1][i], g);
                    }
                    pb[i] ^= 1;
                }
                E0[i] = E1[i]; E1[i] = En; M0[i] = M1[i]; M1[i] = Mn;
            }
            __syncthreads();
        }
#pragma unroll
        for (int i = 0; i < NB4; ++i) {
            float* wsb = ws + (size_t)(NBATCH + b0 + i) * WS_STRIDE;
            if (q == 0)  wsb[jt] = beta[i];       // beta_512 (pow2-scaled)
            if (tid == 0) wsb[128] = (float)kSum[i];
        }
    }
}

// Z = sum_i alpha_MID[i] * beta_MID[i] * 2^(kF+kB)
__global__ __launch_bounds__(64) void crf_combine(
    const float* __restrict__ ws, float* __restrict__ out)
{
    int b    = blockIdx.x;
    int lane = threadIdx.x;
    const float* af = ws + (size_t)b * WS_STRIDE;
    const float* bf = ws + (size_t)(NBATCH + b) * WS_STRIDE;
    float d = af[lane] * bf[lane] + af[lane + 64] * bf[lane + 64];
#pragma unroll
    for (int o = 32; o > 0; o >>= 1) d += __shfl_down(d, o, 64);
    if (lane == 0) {
        float logZ = __logf(d) + (af[128] + bf[128]) * 0.69314718055994531f;
        atomicAdd(out, logZ * (1.0f / NBATCH));
    }
}

extern "C" void kernel_launch(void* const* d_in, const int* in_sizes, int n_in,
                              void* d_out, int out_size, void* d_ws, size_t ws_size,
                              hipStream_t stream) {
    const float* emissions   = (const float*)d_in[0];
    const float* transitions = (const float*)d_in[1];
    const int*   tags        = (const int*)d_in[2];
    const float* mask        = (const float*)d_in[3];
    float*       out         = (float*)d_out;
    float*       ws          = (float*)d_ws;

    hipMemsetAsync(out, 0, sizeof(float), stream);
    crf_chains<<<2 * (NBATCH / NB4) + 32, 512, 0, stream>>>(
        emissions, transitions, tags, mask, out, ws);
    crf_combine<<<NBATCH, 64, 0, stream>>>(ws, out);
}

// Round 19
// 349.235 us; speedup vs baseline: 2.2817x; 2.2817x over previous
//
#include <hip/hip_runtime.h>
#include <stdint.h>

#define SEQ      1024
#define NT       128
#define NBATCH   256
#define MID      512
#define WS_STRIDE 132       // 128 floats + kSum

typedef float v2f __attribute__((ext_vector_type(2)));

// Thread = (jtp, r): owns OUTPUT TAG PAIR {2jtp, 2jtp+1}, predecessor slice
// [16r, 16r+16). Weights: 8 pairs x 2 outputs = 16 packed-bf16 u32 regs
// (the R13-proven-resident size). State-unpack shared across both outputs:
// 2.0 VALU ops/MAC vs R13's 3.0.
#define RALL(X) X(0) X(1) X(2) X(3) X(4) X(5) X(6) X(7)
#define DECLW(k) uint32_t WA##k; uint32_t WB##k;
#define INITW(k) { \
    float a0_ = __expf(wbaseA[(2 * (k)    ) * wstr]); \
    float a1_ = __expf(wbaseA[(2 * (k) + 1) * wstr]); \
    asm("v_cvt_pk_bf16_f32 %0, %1, %2" : "=v"(WA##k) : "v"(a0_), "v"(a1_)); \
    float b0_ = __expf(wbaseB[(2 * (k)    ) * wstr]); \
    float b1_ = __expf(wbaseB[(2 * (k) + 1) * wstr]); \
    asm("v_cvt_pk_bf16_f32 %0, %1, %2" : "=v"(WB##k) : "v"(b0_), "v"(b1_)); }
#define PINW(k)  asm volatile("" : "+v"(WA##k)); asm volatile("" : "+v"(WB##k));

#define UPK(u_) (v2f){ __uint_as_float((u_) << 16), __uint_as_float((u_) & 0xffff0000u) }
#define MC(u_, k_) { \
    v2f s_ = UPK(u_); \
    aA = __builtin_elementwise_fma(UPK(WA##k_), s_, aA); \
    aB = __builtin_elementwise_fma(UPK(WB##k_), s_, aB); }

// 16-pred slice, 2 outputs; cross-r combine (r = lane bits 0..2)
#define MATVEC16x2(SA_, SB_) { \
    v2f aA = {0.f,0.f}, aB = {0.f,0.f}; \
    uint4 u0_ = *(const uint4*)(gp); \
    uint4 u1_ = *(const uint4*)(gp + 4); \
    MC(u0_.x, 0) MC(u0_.y, 1) MC(u0_.z, 2) MC(u0_.w, 3) \
    MC(u1_.x, 4) MC(u1_.y, 5) MC(u1_.z, 6) MC(u1_.w, 7) \
    SA_ = aA.x + aA.y;  SB_ = aB.x + aB.y; \
    SA_ += __shfl_xor(SA_, 1, 64);  SB_ += __shfl_xor(SB_, 1, 64); \
    SA_ += __shfl_xor(SA_, 2, 64);  SB_ += __shfl_xor(SB_, 2, 64); \
    SA_ += __shfl_xor(SA_, 4, 64);  SB_ += __shfl_xor(SB_, 4, 64); }

#define PAIR_STORE(bufp_, vA_, vB_) { \
    uint32_t pk_; \
    asm("v_cvt_pk_bf16_f32 %0, %1, %2" : "=v"(pk_) : "v"(vA_), "v"(vB_)); \
    (bufp_)[jtp] = pk_; }

// blocks [0,256):    forward chains (batch = blk, steps 1..512)
// blocks [256,512):  backward chains (batch = blk-256, steps 1023..513)
// blocks [512,544):  score gathers (8 batches each)
__global__ __launch_bounds__(512) void crf_chains(
    const float* __restrict__ emissions,   // [B, SEQ, NT]
    const float* __restrict__ transitions, // [NT, NT]
    const int*   __restrict__ tags,        // [B, SEQ]
    const float* __restrict__ mask,        // [B, SEQ]
    float* __restrict__ out,               // [1]
    float* __restrict__ ws)                // [2*256*132]
{
    const int blk = blockIdx.x;
    const int tid = threadIdx.x;

    if (blk >= 2 * NBATCH) {
        // ---------------- score blocks ----------------
        int b    = (blk - 2 * NBATCH) * 8 + (tid >> 6);
        int lane = tid & 63;
        const float* emb = emissions + (size_t)b * SEQ * NT;
        const int*   tgb = tags + (size_t)b * SEQ;
        const float* mkb = mask + (size_t)b * SEQ;
        float sc = 0.f;
        for (int t = lane; t < SEQ; t += 64) {
            int   tg = tgb[t];
            float mt = mkb[t];
            sc += emb[t * NT + tg] * mt;
            if (t >= 1) sc += transitions[tgb[t - 1] * NT + tg] * mt;
        }
#pragma unroll
        for (int o = 32; o > 0; o >>= 1) sc += __shfl_down(sc, o, 64);
        if (lane == 0) atomicAdd(out, -sc * (1.0f / NBATCH));
        return;
    }

    // ---------------- chain block ----------------
    // state = 64 u32 bf16 pairs (tags 2i, 2i+1), double-buffered
    __shared__ __align__(16) uint32_t buf[2][NT / 2];

    const int jtp = tid >> 3;   // owned output tag pair 0..63 (tags 2jtp, 2jtp+1)
    const int r   = tid & 7;    // predecessor slice (16 tags)

    const bool fwd = (blk < NBATCH);
    const int  b   = fwd ? blk : blk - NBATCH;

    const float* emb = emissions + (size_t)b * SEQ * NT;
    const float* mkb = mask + (size_t)b * SEQ;

    // fwd: W[pred][out] col-pair (stride NT); bwd: W[out][pred] row (contig)
    const float* wbaseA = fwd ? (transitions + (size_t)(16 * r) * NT + 2 * jtp)
                              : (transitions + (size_t)(2 * jtp) * NT + 16 * r);
    const float* wbaseB = wbaseA + (fwd ? 1 : NT);
    const int    wstr   = fwd ? NT : 1;

    RALL(DECLW)
    RALL(INITW)
    RALL(PINW)

    int   kSum = 0, p = 0;
    float gA = 0.f, gB = 0.f, betaA = 1.0f, betaB = 1.0f;
    float2 E0, E1;
    float  M0, M1;

    if (fwd) {
        gA = __expf(emb[2 * jtp]);
        gB = __expf(emb[2 * jtp + 1]);
        if (r == 0) PAIR_STORE(buf[0], gA, gB);
        E0 = *(const float2*)(emb + 1 * NT + 2 * jtp);
        E1 = *(const float2*)(emb + 2 * NT + 2 * jtp);
        M0 = mkb[1];  M1 = mkb[2];
    } else {
        float wA = __expf(emb[(size_t)(SEQ - 1) * NT + 2 * jtp]);
        float wB = __expf(emb[(size_t)(SEQ - 1) * NT + 2 * jtp + 1]);
        if (r == 0) PAIR_STORE(buf[0], wA, wB);
        E0 = *(const float2*)(emb + (size_t)(SEQ - 2) * NT + 2 * jtp);
        E1 = *(const float2*)(emb + (size_t)(SEQ - 3) * NT + 2 * jtp);
        M0 = mkb[SEQ - 1];  M1 = mkb[SEQ - 2];
    }
    __syncthreads();

    if (fwd) {
        // ---------- forward: 512 steps, t = 1+s ----------
        for (int s = 0; s < MID; ++s) {
            float2 En = *(const float2*)(emb + (size_t)(3 + s) * NT + 2 * jtp);
            float  Mn = mkb[3 + s];
            if (M0 != 0.0f) {
                const uint32_t* gp = buf[p] + 8 * r;
                uint32_t anchor = buf[p][0];
                float sA, sB;
                MATVEC16x2(sA, sB);
                int   e  = (int)((anchor >> 7) & 0xff);   // bf16 exp of tag0
                float rc = __uint_as_float((uint32_t)(254 - e) << 23);
                kSum += e - 127;
                if (r == 0) {
                    gA = sA * rc * __expf(E0.x);
                    gB = sB * rc * __expf(E0.y);
                    PAIR_STORE(buf[p ^ 1], gA, gB);
                }
                p ^= 1;
            }
            __syncthreads();
            E0 = E1; E1 = En; M0 = M1; M1 = Mn;
        }
        float* wsb = ws + (size_t)b * WS_STRIDE;
        if (r == 0) *(float2*)(wsb + 2 * jtp) = make_float2(gA, gB);  // alpha_512
        if (tid == 0) wsb[128] = (float)kSum;
    } else {
        // ---------- backward: 511 steps, t = 1023-s; buf holds w = beta.*expE ----------
        for (int s = 0; s < MID - 1; ++s) {
            float2 En = *(const float2*)(emb + (size_t)(SEQ - 4 - s) * NT + 2 * jtp);
            float  Mn = mkb[SEQ - 3 - s];
            {
                const uint32_t* gp = buf[p] + 8 * r;
                uint32_t anchor = buf[p][0];
                float sA, sB;
                MATVEC16x2(sA, sB);
                int   e  = (int)((anchor >> 7) & 0xff);
                float rc = __uint_as_float((uint32_t)(254 - e) << 23);
                kSum += e - 127;
                float bnA = (M0 != 0.0f) ? sA * rc : betaA * rc;
                float bnB = (M0 != 0.0f) ? sB * rc : betaB * rc;
                betaA = bnA;  betaB = bnB;
                if (r == 0) {
                    float wA = bnA * __expf(E0.x);   // w_{t-1}
                    float wB = bnB * __expf(E0.y);
                    PAIR_STORE(buf[p ^ 1], wA, wB);
                }
                p ^= 1;
            }
            __syncthreads();
            E0 = E1; E1 = En; M0 = M1; M1 = Mn;
        }
        float* wsb = ws + (size_t)(NBATCH + b) * WS_STRIDE;
        if (r == 0) *(float2*)(wsb + 2 * jtp) = make_float2(betaA, betaB);  // beta_512
        if (tid == 0) wsb[128] = (float)kSum;
    }
}

// Z = sum_i alpha_MID[i] * beta_MID[i] * 2^(kF+kB)
__global__ __launch_bounds__(64) void crf_combine(
    const float* __restrict__ ws, float* __restrict__ out)
{
    int b    = blockIdx.x;
    int lane = threadIdx.x;
    const float* af = ws + (size_t)b * WS_STRIDE;
    const float* bf = ws + (size_t)(NBATCH + b) * WS_STRIDE;
    float d = af[lane] * bf[lane] + af[lane + 64] * bf[lane + 64];
#pragma unroll
    for (int o = 32; o > 0; o >>= 1) d += __shfl_down(d, o, 64);
    if (lane == 0) {
        float logZ = __logf(d) + (af[128] + bf[128]) * 0.69314718055994531f;
        atomicAdd(out, logZ * (1.0f / NBATCH));
    }
}

extern "C" void kernel_launch(void* const* d_in, const int* in_sizes, int n_in,
                              void* d_out, int out_size, void* d_ws, size_t ws_size,
                              hipStream_t stream) {
    const float* emissions   = (const float*)d_in[0];
    const float* transitions = (const float*)d_in[1];
    const int*   tags        = (const int*)d_in[2];
    const float* mask        = (const float*)d_in[3];
    float*       out         = (float*)d_out;
    float*       ws          = (float*)d_ws;

    hipMemsetAsync(out, 0, sizeof(float), stream);
    crf_chains<<<2 * NBATCH + 32, 512, 0, stream>>>(
        emissions, transitions, tags, mask, out, ws);
    crf_combine<<<NBATCH, 64, 0, stream>>>(ws, out);
}

// Round 20
// 317.504 us; speedup vs baseline: 2.5097x; 1.0999x over previous
//
#include <hip/hip_runtime.h>
#include <stdint.h>

#define SEQ      1024
#define NT       128
#define NBATCH   256
#define MID      512
#define WS_STRIDE 132       // 128 floats + kSum

// Barrier that drains ONLY LDS (state-write visibility) and leaves global
// prefetch loads in flight -- __syncthreads() would add vmcnt(0) and force
// the just-issued HBM emission prefetch to complete every step.
#define BARRIER() asm volatile("s_waitcnt lgkmcnt(0)\n\ts_barrier" ::: "memory")

// emulated bf16-pair dot (R13-proven): 6 ops/pair
#define DOT2ACC(a, su, wu) { \
    a = fmaf(__uint_as_float((wu) << 16),         __uint_as_float((su) << 16),         a); \
    a = fmaf(__uint_as_float((wu) & 0xffff0000u), __uint_as_float((su) & 0xffff0000u), a); }

// 16 NAMED u32 weight regs (bf16 pairs) = 16 VGPRs -> total live ~28
// (R13-proven resident; all larger demands spilled).
#define RALL(X) X(0) X(1) X(2) X(3) X(4) X(5) X(6) X(7) \
                X(8) X(9) X(10) X(11) X(12) X(13) X(14) X(15)
#define DECLW(k) uint32_t W##k;
#define INITW(k) { \
    float f0_ = __expf(wbase[(2 * (k)    ) * wstr]); \
    float f1_ = __expf(wbase[(2 * (k) + 1) * wstr]); \
    asm("v_cvt_pk_bf16_f32 %0, %1, %2" : "=v"(W##k) : "v"(f0_), "v"(f1_)); }
#define PINW(k)  asm volatile("" : "+v"(W##k));

#define MQ(c, k0, k1, k2, k3) { \
    uint4 u_ = *(const uint4*)(gp + 4 * (c)); \
    DOT2ACC(a0, u_.x, W##k0); \
    DOT2ACC(a1, u_.y, W##k1); \
    DOT2ACC(a2, u_.z, W##k2); \
    DOT2ACC(a3, u_.w, W##k3); }

// 32-tag quarter dot (16 pairs) + cross-q combine (partners = adjacent lanes)
#define MATVEC32(S_) { \
    float a0 = 0.f, a1 = 0.f, a2 = 0.f, a3 = 0.f; \
    MQ(0,0,1,2,3) MQ(1,4,5,6,7) MQ(2,8,9,10,11) MQ(3,12,13,14,15) \
    S_ = (a0 + a1) + (a2 + a3); \
    S_ += __shfl_xor(S_, 1, 64); \
    S_ += __shfl_xor(S_, 2, 64); }

#define BF16_STORE(bufp_, val_) { \
    uint32_t pk_; \
    asm("v_cvt_pk_bf16_f32 %0, %1, %2" : "=v"(pk_) : "v"(val_), "v"(val_)); \
    ((unsigned short*)(bufp_))[jt] = (unsigned short)(pk_ & 0xffffu); }

// blocks [0,256):    forward chains (batch = blk, steps 1..512)
// blocks [256,512):  backward chains (batch = blk-256, steps 1023..513)
// blocks [512,544):  score gathers (8 batches each)
__global__ __launch_bounds__(512) void crf_chains(
    const float* __restrict__ emissions,   // [B, SEQ, NT]
    const float* __restrict__ transitions, // [NT, NT]
    const int*   __restrict__ tags,        // [B, SEQ]
    const float* __restrict__ mask,        // [B, SEQ]
    float* __restrict__ out,               // [1]
    float* __restrict__ ws)                // [2*256*132]
{
    const int blk = blockIdx.x;
    const int tid = threadIdx.x;

    if (blk >= 2 * NBATCH) {
        // ---------------- score blocks ----------------
        int b    = (blk - 2 * NBATCH) * 8 + (tid >> 6);
        int lane = tid & 63;
        const float* emb = emissions + (size_t)b * SEQ * NT;
        const int*   tgb = tags + (size_t)b * SEQ;
        const float* mkb = mask + (size_t)b * SEQ;
        float sc = 0.f;
        for (int t = lane; t < SEQ; t += 64) {
            int   tg = tgb[t];
            float mt = mkb[t];
            sc += emb[t * NT + tg] * mt;
            if (t >= 1) sc += transitions[tgb[t - 1] * NT + tg] * mt;
        }
#pragma unroll
        for (int o = 32; o > 0; o >>= 1) sc += __shfl_down(sc, o, 64);
        if (lane == 0) atomicAdd(out, -sc * (1.0f / NBATCH));
        return;
    }

    // ---------------- chain block ----------------
    // state = 64 u32 bf16 pairs (tags 2i, 2i+1), double-buffered
    __shared__ __align__(16) uint32_t buf[2][NT / 2];

    const int jt = tid >> 2;   // owned output tag 0..127
    const int q  = tid & 3;    // predecessor quarter (32 tags)

    const bool fwd = (blk < NBATCH);
    const int  b   = fwd ? blk : blk - NBATCH;

    const float* emb = emissions + (size_t)b * SEQ * NT;
    const float* mkb = mask + (size_t)b * SEQ;

    // fwd: expT[32q+2k][jt] (col jt, stride NT); bwd: expT[jt][32q+2k] (row, contig)
    const float* wbase = fwd ? (transitions + (size_t)(32 * q) * NT + jt)
                             : (transitions + (size_t)jt * NT + 32 * q);
    const int    wstr  = fwd ? NT : 1;

    RALL(DECLW)
    RALL(INITW)
    RALL(PINW)

    int   kSum = 0, p = 0;
    float gcur = 0.f, beta = 1.0f;
    float E0, E1, M0, M1;

    if (fwd) {
        gcur = __expf(emb[jt]);
        if (q == 0) BF16_STORE(buf[0], gcur);
        E0 = emb[1 * NT + jt];  E1 = emb[2 * NT + jt];
        M0 = mkb[1];            M1 = mkb[2];
    } else {
        float w0 = __expf(emb[(size_t)(SEQ - 1) * NT + jt]);   // w_1023 (beta=1)
        if (q == 0) BF16_STORE(buf[0], w0);
        E0 = emb[(size_t)(SEQ - 2) * NT + jt];
        E1 = emb[(size_t)(SEQ - 3) * NT + jt];
        M0 = mkb[SEQ - 1];      M1 = mkb[SEQ - 2];
    }
    __syncthreads();

    if (fwd) {
        // ---------- forward: 512 steps, t = 1+s ----------
        for (int s = 0; s < MID; ++s) {
            float En = emb[(size_t)(3 + s) * NT + jt];   // <= 514
            float Mn = mkb[3 + s];
            const bool resc = ((s & 3) == 3);
            if (M0 != 0.0f) {
                const uint32_t* gp = buf[p] + 16 * q;
                float rc = 1.0f;
                if (resc) {
                    uint32_t anchor = buf[p][0];
                    int e = (int)((anchor >> 7) & 0xff);   // bf16 exp of tag0
                    rc = __uint_as_float((uint32_t)(254 - e) << 23);  // 2^-(e-127)
                    kSum += e - 127;
                }
                float sres;
                MATVEC32(sres);
                if (q == 0) {
                    gcur = sres * rc * __expf(E0);
                    BF16_STORE(buf[p ^ 1], gcur);
                }
                p ^= 1;
            }
            BARRIER();
            E0 = E1; E1 = En; M0 = M1; M1 = Mn;
        }
        float* wsb = ws + (size_t)b * WS_STRIDE;
        if (q == 0)  wsb[jt] = gcur;          // alpha_512 (pow2-scaled)
        if (tid == 0) wsb[128] = (float)kSum;
    } else {
        // ---------- backward: 511 steps, t = 1023-s; buf holds w = beta.*expE ----------
        for (int s = 0; s < MID - 1; ++s) {
            float En = emb[(size_t)(SEQ - 4 - s) * NT + jt];  // >= 510
            float Mn = mkb[SEQ - 3 - s];
            const bool resc = ((s & 3) == 3);
            {
                const uint32_t* gp = buf[p] + 16 * q;
                float rc = 1.0f;
                if (resc) {
                    uint32_t anchor = buf[p][0];
                    int e = (int)((anchor >> 7) & 0xff);
                    rc = __uint_as_float((uint32_t)(254 - e) << 23);
                    kSum += e - 127;
                }
                float sres;
                MATVEC32(sres);
                float bn = (M0 != 0.0f) ? sres * rc : beta * rc;
                beta = bn;
                if (q == 0) {
                    float g = bn * __expf(E0);   // w_{t-1}
                    BF16_STORE(buf[p ^ 1], g);
                }
                p ^= 1;
            }
            BARRIER();
            E0 = E1; E1 = En; M0 = M1; M1 = Mn;
        }
        float* wsb = ws + (size_t)(NBATCH + b) * WS_STRIDE;
        if (q == 0)  wsb[jt] = beta;          // beta_512 (pow2-scaled)
        if (tid == 0) wsb[128] = (float)kSum;
    }
}

// Z = sum_i alpha_MID[i] * beta_MID[i] * 2^(kF+kB)
__global__ __launch_bounds__(64) void crf_combine(
    const float* __restrict__ ws, float* __restrict__ out)
{
    int b    = blockIdx.x;
    int lane = threadIdx.x;
    const float* af = ws + (size_t)b * WS_STRIDE;
    const float* bf = ws + (size_t)(NBATCH + b) * WS_STRIDE;
    float d = af[lane] * bf[lane] + af[lane + 64] * bf[lane + 64];
#pragma unroll
    for (int o = 32; o > 0; o >>= 1) d += __shfl_down(d, o, 64);
    if (lane == 0) {
        float logZ = __logf(d) + (af[128] + bf[128]) * 0.69314718055994531f;
        atomicAdd(out, logZ * (1.0f / NBATCH));
    }
}

extern "C" void kernel_launch(void* const* d_in, const int* in_sizes, int n_in,
                              void* d_out, int out_size, void* d_ws, size_t ws_size,
                              hipStream_t stream) {
    const float* emissions   = (const float*)d_in[0];
    const float* transitions = (const float*)d_in[1];
    const int*   tags        = (const int*)d_in[2];
    const float* mask        = (const float*)d_in[3];
    float*       out         = (float*)d_out;
    float*       ws          = (float*)d_ws;

    hipMemsetAsync(out, 0, sizeof(float), stream);
    crf_chains<<<2 * NBATCH + 32, 512, 0, stream>>>(
        emissions, transitions, tags, mask, out, ws);
    crf_combine<<<NBATCH, 64, 0, stream>>>(ws, out);
}